// Round 5
// baseline (663.503 us; speedup 1.0000x reference)
//
#include <hip/hip_runtime.h>
#include <cstdint>

// TriplaneEncoding, fp32 I/O. N=2^20 points, 4 levels (r=128,256,512,1024),
// C=4, 3 planes.  out[n, l*12 + p*4 + c] = plane_bilinear * line
// Line sample is degenerate (W=1 axis carries the coord, H axis fixed 0):
//   line = w(t) * 0.5*(TL[p,c,r/2-1] + TL[p,c,r/2]).
//
// History: R1-R3 crashed (inputs are INTERLEAVED x,tp0,tl0,tp1,tl1,... —
// triline read as triplane = 24MB OOB). R4's NaN proved I/O is fp32, not bf16
// (fp32 words read as bf16 halves -> exp 0xFF patterns -> NaN).
// Design: planes repacked channel-last (3, r*r, C) fp32 in d_ws so each
// bilinear corner is ONE float4 load instead of 4 r^2-strided scalar gathers.

// Workspace layout in floats:
static constexpr int LVL_OFF[4] = {0, 196608, 983040, 4128768};
static constexpr int S_OFF = 16711680;   // 48 fp32 line constants after planes
static constexpr size_t WS_NEED = (size_t)(S_OFF + 48) * sizeof(float);

// ---------------- repack one level: (3, C, r, r) -> (3, r*r, C) ----------------
__global__ __launch_bounds__(256) void repack_lvl(const float* __restrict__ src,
                                                  float* __restrict__ dst,
                                                  int rr_shift /* log2(r*r) */) {
    int j = blockIdx.x * blockDim.x + threadIdx.x;   // output float index, 12*r*r
    int c  = j & 3;
    int t  = j >> 2;
    int p  = t >> rr_shift;
    int yx = t & ((1 << rr_shift) - 1);
    dst[j] = src[(((size_t)(p * 4 + c)) << rr_shift) + yx];
}

// ---------------- line constants: 48 fp32 ----------------
__global__ void line_consts(const float* __restrict__ tl0, const float* __restrict__ tl1,
                            const float* __restrict__ tl2, const float* __restrict__ tl3,
                            float* __restrict__ s_out) {
    int i = threadIdx.x;
    if (i >= 48) return;
    int l = i / 12, rem = i % 12, p = rem >> 2, c = rem & 3;
    const float* tl = (l == 0) ? tl0 : (l == 1) ? tl1 : (l == 2) ? tl2 : tl3;
    int r = 128 << l;
    const float* row = tl + (size_t)((p << 2) + c) * r;
    int y0 = (r >> 1) - 1;                 // rows r/2-1, r/2, wy = 0.5 exactly
    s_out[i] = 0.5f * row[y0] + 0.5f * row[y0 + 1];
}

// ---------------- bilinear helpers ----------------
struct BilinW {
    int i00, i10, i01, i11;     // clamped linear indices (y*r + x)
    float w00, w10, w01, w11;   // weights * validity (zero padding)
};

__device__ __forceinline__ BilinW bilin_weights(int r, float u, float v) {
    float fr = (float)r;
    float fx = (u + 1.0f) * 0.5f * fr - 0.5f;
    float fy = (v + 1.0f) * 0.5f * fr - 0.5f;
    float x0f = floorf(fx), y0f = floorf(fy);
    float wx = fx - x0f, wy = fy - y0f;
    int x0 = (int)x0f, y0 = (int)y0f;
    int x1 = x0 + 1, y1 = y0 + 1;
    float vx0 = ((unsigned)x0 < (unsigned)r) ? 1.0f : 0.0f;
    float vx1 = ((unsigned)x1 < (unsigned)r) ? 1.0f : 0.0f;
    float vy0 = ((unsigned)y0 < (unsigned)r) ? 1.0f : 0.0f;
    float vy1 = ((unsigned)y1 < (unsigned)r) ? 1.0f : 0.0f;
    int x0c = min(max(x0, 0), r - 1), x1c = min(max(x1, 0), r - 1);
    int y0c = min(max(y0, 0), r - 1), y1c = min(max(y1, 0), r - 1);
    BilinW b;
    b.i00 = y0c * r + x0c; b.i10 = y0c * r + x1c;
    b.i01 = y1c * r + x0c; b.i11 = y1c * r + x1c;
    b.w00 = (1.0f - wx) * (1.0f - wy) * vx0 * vy0;
    b.w10 = wx * (1.0f - wy) * vx1 * vy0;
    b.w01 = (1.0f - wx) * wy * vx0 * vy1;
    b.w11 = wx * wy * vx1 * vy1;
    return b;
}

__device__ __forceinline__ float line_w(float t) {
    float fx = (t + 1.0f) * 0.5f - 0.5f;     // W = 1 axis
    float x0f = floorf(fx);
    float wx = fx - x0f;
    int x0 = (int)x0f;
    float w = 0.0f;
    if (x0 == 0) w += 1.0f - wx;     // col 0 valid as "left" corner
    if (x0 == -1) w += wx;           // col 0 valid as "right" corner
    return w;
}

// ---------------- main kernel (repacked path) ----------------
template <bool VEC4OUT>
__global__ __launch_bounds__(256) void tri_main(const float* __restrict__ x,
                                                const float4* __restrict__ planes,
                                                const float* __restrict__ S,
                                                float* __restrict__ out, int N) {
    int n = blockIdx.x * blockDim.x + threadIdx.x;
    if (n >= N) return;
    float ax = x[n * 3 + 0] * 2.0f - 1.0f;
    float ay = x[n * 3 + 1] * 2.0f - 1.0f;
    float az = x[n * 3 + 2] * 2.0f - 1.0f;
    // plane p (u = W axis, v = H axis): p0:(x,z) p1:(y,x) p2:(z,y)
    const float U[3] = {ax, ay, az};
    const float V[3] = {az, ax, ay};
    const float LW[3] = {line_w(ax), line_w(ay), line_w(az)};

#pragma unroll
    for (int l = 0; l < 4; ++l) {
        const int r = 128 << l;
#pragma unroll
        for (int p = 0; p < 3; ++p) {
            const float4* G = planes + (LVL_OFF[l] >> 2) + (size_t)p * r * r;
            BilinW b = bilin_weights(r, U[p], V[p]);
            float4 g00 = G[b.i00], g10 = G[b.i10], g01 = G[b.i01], g11 = G[b.i11];
            float w = LW[p];
            float sx = S[(l * 3 + p) * 4 + 0] * w;
            float sy = S[(l * 3 + p) * 4 + 1] * w;
            float sz = S[(l * 3 + p) * 4 + 2] * w;
            float sw = S[(l * 3 + p) * 4 + 3] * w;
            float4 o;
            o.x = (g00.x * b.w00 + g10.x * b.w10 + g01.x * b.w01 + g11.x * b.w11) * sx;
            o.y = (g00.y * b.w00 + g10.y * b.w10 + g01.y * b.w01 + g11.y * b.w11) * sy;
            o.z = (g00.z * b.w00 + g10.z * b.w10 + g01.z * b.w01 + g11.z * b.w11) * sz;
            o.w = (g00.w * b.w00 + g10.w * b.w10 + g01.w * b.w01 + g11.w * b.w11) * sw;
            size_t base = (size_t)n * 48 + (size_t)(l * 12 + p * 4);
            if (VEC4OUT) {
                *reinterpret_cast<float4*>(out + base) = o;
            } else {
                out[base + 0] = o.x; out[base + 1] = o.y;
                out[base + 2] = o.z; out[base + 3] = o.w;
            }
        }
    }
}

// ---------------- fallback: direct layout, scalar I/O ----------------
__global__ __launch_bounds__(256) void tri_direct(
        const float* __restrict__ x,
        const float* __restrict__ tp0, const float* __restrict__ tp1,
        const float* __restrict__ tp2, const float* __restrict__ tp3,
        const float* __restrict__ tl0, const float* __restrict__ tl1,
        const float* __restrict__ tl2, const float* __restrict__ tl3,
        float* __restrict__ out, int N) {
    int n = blockIdx.x * blockDim.x + threadIdx.x;
    if (n >= N) return;
    float ax = x[n * 3 + 0] * 2.0f - 1.0f;
    float ay = x[n * 3 + 1] * 2.0f - 1.0f;
    float az = x[n * 3 + 2] * 2.0f - 1.0f;
    const float U[3] = {ax, ay, az};
    const float V[3] = {az, ax, ay};
    const float LW[3] = {line_w(ax), line_w(ay), line_w(az)};
    const float* TP[4] = {tp0, tp1, tp2, tp3};
    const float* TL[4] = {tl0, tl1, tl2, tl3};

#pragma unroll
    for (int l = 0; l < 4; ++l) {
        const int r = 128 << l;
        const int rr = r * r;
        const int y0 = (r >> 1) - 1;
#pragma unroll
        for (int p = 0; p < 3; ++p) {
            const float* G = TP[l] + (size_t)(p * 4) * rr;
            BilinW b = bilin_weights(r, U[p], V[p]);
            const float w = LW[p];
#pragma unroll
            for (int c = 0; c < 4; ++c) {
                const float* Gc = G + (size_t)c * rr;
                float acc = Gc[b.i00] * b.w00 + Gc[b.i10] * b.w10 +
                            Gc[b.i01] * b.w01 + Gc[b.i11] * b.w11;
                const float* row = TL[l] + (size_t)((p << 2) + c) * r;
                float s = 0.5f * row[y0] + 0.5f * row[y0 + 1];
                out[(size_t)n * 48 + l * 12 + p * 4 + c] = acc * (s * w);
            }
        }
    }
}

extern "C" void kernel_launch(void* const* d_in, const int* in_sizes, int n_in,
                              void* d_out, int out_size, void* d_ws, size_t ws_size,
                              hipStream_t stream) {
    const float* x = (const float*)d_in[0];
    const float* tp[4];
    const float* tl[4];
    // setup_inputs() dict order is interleaved: x, tp0, tl0, tp1, tl1, ...
    // (triline_0 has 3*4*128 = 1536 elements; triplane_0 has 196608).
    bool interleaved = (n_in >= 9) && (in_sizes[2] == 1536);
    for (int l = 0; l < 4; ++l) {
        if (interleaved) {
            tp[l] = (const float*)d_in[1 + 2 * l];
            tl[l] = (const float*)d_in[2 + 2 * l];
        } else {
            tp[l] = (const float*)d_in[1 + l];
            tl[l] = (const float*)d_in[5 + l];
        }
    }
    int N = in_sizes[0] / 3;
    float* out = (float*)d_out;
    int grid = (N + 255) / 256;

    bool ws_ok = (ws_size >= WS_NEED) && (((uintptr_t)d_ws & 15u) == 0);
    if (ws_ok) {
        float* ws = (float*)d_ws;
        for (int l = 0; l < 4; ++l) {
            int r = 128 << l;
            int total = 12 * r * r;                // floats; multiple of 256
            int rr_shift = 2 * (7 + l);
            repack_lvl<<<total / 256, 256, 0, stream>>>(tp[l], ws + LVL_OFF[l], rr_shift);
        }
        line_consts<<<1, 64, 0, stream>>>(tl[0], tl[1], tl[2], tl[3], ws + S_OFF);
        if (((uintptr_t)d_out & 15u) == 0) {
            tri_main<true><<<grid, 256, 0, stream>>>(x, (const float4*)ws, ws + S_OFF, out, N);
        } else {
            tri_main<false><<<grid, 256, 0, stream>>>(x, (const float4*)ws, ws + S_OFF, out, N);
        }
    } else {
        tri_direct<<<grid, 256, 0, stream>>>(
            x, tp[0], tp[1], tp[2], tp[3], tl[0], tl[1], tl[2], tl[3], out, N);
    }
}